// Round 4
// baseline (3937.015 us; speedup 1.0000x reference)
//
#include <hip/hip_runtime.h>

#define TT 512
#define BB 64
#define EE 256
#define HH 512
#define NWG 256
#define THREADS 256
#define BBHH (BB * HH)

// ws byte offsets
#define WS_REG      0u           // u32[16]: [0]=gcnt [1..8]=per-XCD cnt [9]=mode
#define WS_FLAGSL   64u          // u32[8][4][32] = 4096 B
#define WS_FLAGSG   4160u        // u32[4][32] = 512 B
#define WS_HBUFL    65536u       // 8 XCD * 2 parity * 65536 B = 1 MB
#define WS_HBUFG    1114112u     // 2 * 65536 B
#define WS_HOUT     1245184u     // 64 KB
#define WS_XE       1310720u     // 16 MB
#define WS_ZERO_U32 311296u      // zero bytes [0, 1245184)

typedef unsigned short u16;
typedef unsigned int u32;
typedef unsigned long long u64;
typedef __attribute__((ext_vector_type(8))) short bh8;
typedef __attribute__((ext_vector_type(4))) float f32x4;

__device__ __forceinline__ u16 f2b(float f) {
  union { float f; u32 u; } v; v.f = f;
  return (u16)((v.u + 0x7fffu + ((v.u >> 16) & 1u)) >> 16);
}
__device__ __forceinline__ float b2f(u16 b) {
  union { u32 u; float f; } v; v.u = ((u32)b) << 16; return v.f;
}
__device__ __forceinline__ float sigm(float x) { return 1.f / (1.f + __expf(-x)); }
__device__ __forceinline__ float tanh_f(float x) {
  float e = __expf(2.f * x);
  return 1.f - 2.f / (e + 1.f);
}

// mode-dependent memory ops. local: sc0 (XCD L2 = coherence point).
// fallback: sc0 sc1 (IF = coherence point, round-2-proven encoding).
__device__ __forceinline__ bh8 ldh(const u16* p, bool loc) {
  bh8 v;
  if (loc) asm volatile("global_load_dwordx4 %0, %1, off sc0"     : "=v"(v) : "v"(p));
  else     asm volatile("global_load_dwordx4 %0, %1, off sc0 sc1" : "=v"(v) : "v"(p));
  return v;
}
__device__ __forceinline__ void st32(u32* p, u32 v, bool loc) {
  if (loc) asm volatile("global_store_dword %0, %1, off sc0"     :: "v"(p), "v"(v) : "memory");
  else     asm volatile("global_store_dword %0, %1, off sc0 sc1" :: "v"(p), "v"(v) : "memory");
}
__device__ __forceinline__ u32 ldf(const u32* p, bool loc) {
  u32 v;
  if (loc) asm volatile("global_load_dword %0, %1, off sc0\n\ts_waitcnt vmcnt(0)"
                        : "=v"(v) : "v"(p) : "memory");
  else     asm volatile("global_load_dword %0, %1, off sc0 sc1\n\ts_waitcnt vmcnt(0)"
                        : "=v"(v) : "v"(p) : "memory");
  return v;
}

// ---- kernel 0: zero control region (flags, counters, h parity buffers) ----
__global__ void k_init(u32* __restrict__ z) {
  const u32 gid = blockIdx.x * 256 + threadIdx.x;
  if (gid < WS_ZERO_U32) z[gid] = 0u;
}

// ---- kernel 1: xe[t][b][e] = bf16(emb[x[t,b]][e]) ----
__global__ __launch_bounds__(256) void k_embed(const int* __restrict__ x,
    const float* __restrict__ emb, u16* __restrict__ xe)
{
  const int gid = blockIdx.x * 256 + threadIdx.x;
  const int tb  = gid >> 5;
  const int e0  = (gid & 31) << 3;
  const int tok = x[tb];
  const float4* s = (const float4*)(emb + (size_t)tok * EE + e0);
  float4 a = s[0], b = s[1];
  u16 o[8] = { f2b(a.x), f2b(a.y), f2b(a.z), f2b(a.w),
               f2b(b.x), f2b(b.y), f2b(b.z), f2b(b.w) };
  *(uint4*)(xe + (size_t)tb * EE + e0) = *(uint4*)o;
}

// ---- kernel 2: XCD-redundant persistent LSTM ----
// 256 WGs, 1/CU (96KB LDS) => exactly 32 WGs per XCD by capacity. Each XCD
// computes the FULL h update redundantly; h + flags exchanged through the
// XCD's own L2 (sc0). WG slot s owns hidden units [16s,16s+16) -> gate tiles
// i/f/g/o of 16 units each. Wave v owns batch rows [16v,16v+16) (4 independent
// sync groups of 32 waves per XCD). W_ih lives in VGPRs as B-fragments.
__global__ __launch_bounds__(THREADS, 1) void k_lstm(
    const float* __restrict__ Whh, const float* __restrict__ Wih,
    const float* __restrict__ bih, const float* __restrict__ bhh,
    const u16* __restrict__ xe, const int* __restrict__ xlen,
    u32* regp, u32* flagsL, u32* flagsG, u16* hbufL, u16* hbufG,
    u16* hout)
{
  extern __shared__ u16 lWhh[];   // 64 KB used (96 KB alloc forces 1 WG/CU)

  const int tid  = threadIdx.x;
  const int wave = tid >> 6;
  const int lane = tid & 63;
  const int n16  = lane & 15;
  const int grp  = lane >> 4;

  // ---- registration: per-XCD slot + device-wide mode agreement ----
  __shared__ u32 sh[4];
  if (tid == 0) {
    u32 xcd;
    asm volatile("s_getreg_b32 %0, hwreg(HW_REG_XCC_ID)" : "=s"(xcd));
    xcd &= 7u;
    u32 sx = __hip_atomic_fetch_add(&regp[1 + xcd], 1u, __ATOMIC_RELAXED, __HIP_MEMORY_SCOPE_AGENT);
    asm volatile("s_waitcnt vmcnt(0)" ::: "memory");   // cx-add globally done first
    u32 gs = __hip_atomic_fetch_add(&regp[0], 1u, __ATOMIC_RELAXED, __HIP_MEMORY_SCOPE_AGENT);
    asm volatile("s_waitcnt vmcnt(0)" ::: "memory");
    u64 t0; asm volatile("s_memtime %0" : "=s"(t0));
    bool timeout = false;
    while (__hip_atomic_load(&regp[0], __ATOMIC_RELAXED, __HIP_MEMORY_SCOPE_AGENT) < (u32)NWG) {
      u64 tn; asm volatile("s_memtime %0" : "=s"(tn));
      if (tn - t0 > 100000000ull) { timeout = true; break; }
      __builtin_amdgcn_s_sleep(1);
    }
    u32 propose = 2u;  // fallback
    if (!timeout) {
      bool ok = true;
      #pragma unroll
      for (int j = 0; j < 8; ++j)
        ok &= (__hip_atomic_load(&regp[1 + j], __ATOMIC_RELAXED, __HIP_MEMORY_SCOPE_AGENT) == (u32)(NWG / 8));
      propose = ok ? 1u : 2u;
    }
    u32 expd = 0u;
    bool won = __hip_atomic_compare_exchange_strong(&regp[9], &expd, propose,
                   __ATOMIC_RELAXED, __ATOMIC_RELAXED, __HIP_MEMORY_SCOPE_AGENT);
    u32 mode = won ? propose : expd;
    if (mode == 1u && timeout) {  // decider proved full registration; wait it out
      while (__hip_atomic_load(&regp[0], __ATOMIC_RELAXED, __HIP_MEMORY_SCOPE_AGENT) < (u32)NWG)
        __builtin_amdgcn_s_sleep(1);
    }
    sh[0] = (mode == 1u) ? sx : gs;
    sh[1] = mode;
    sh[2] = xcd;
  }
  __syncthreads();
  const u32  slot  = sh[0];
  const bool local = (sh[1] == 1u);
  const u32  xcd   = sh[2];
  if (!local && slot >= 32u) return;   // fallback spare: whole WG exits

  // ---- W_ih -> 32 B-fragments in VGPRs (q=gate tile, kk=K-chunk of 32) ----
  bh8 wihf[32];
  #pragma unroll
  for (int q = 0; q < 4; ++q) {
    #pragma unroll
    for (int kk = 0; kk < 8; ++kk) {
      const float4* s = (const float4*)(Wih + (size_t)(q * HH + slot * 16 + n16) * EE + kk * 32 + grp * 8);
      float4 a = s[0], b = s[1];
      u16 tmp[8] = { f2b(a.x), f2b(a.y), f2b(a.z), f2b(a.w),
                     f2b(b.x), f2b(b.y), f2b(b.z), f2b(b.w) };
      wihf[q * 8 + kk] = *(bh8*)tmp;
    }
  }

  // ---- W_hh slice (64 gate rows x 512) -> LDS bf16, XOR-swizzled ----
  #pragma unroll
  for (int it = 0; it < 16; ++it) {
    int idx = it * THREADS + tid;          // 4096 chunks of 8 cols
    int n   = idx >> 6;
    int c0  = (idx & 63) << 3;
    int grow = (n >> 4) * HH + slot * 16 + (n & 15);
    const float4* s = (const float4*)(Whh + (size_t)grow * HH + c0);
    float4 a = s[0], b = s[1];
    u16 tmp[8] = { f2b(a.x), f2b(a.y), f2b(a.z), f2b(a.w),
                   f2b(b.x), f2b(b.y), f2b(b.z), f2b(b.w) };
    *(uint4*)((char*)lWhh + (u32)(n * 1024 + ((c0 << 1) ^ ((n & 7) << 4)))) = *(uint4*)tmp;
  }

  // per-lane gate biases (unit = slot*16 + n16)
  float bsq[4];
  #pragma unroll
  for (int q = 0; q < 4; ++q)
    bsq[q] = bih[q * HH + slot * 16 + n16] + bhh[q * HH + slot * 16 + n16];

  int   lenr[4];
  float cst[4] = {0.f, 0.f, 0.f, 0.f};
  float hst[4] = {0.f, 0.f, 0.f, 0.f};
  #pragma unroll
  for (int j = 0; j < 4; ++j) lenr[j] = xlen[wave * 16 + grp * 4 + j];
  int wmax = lenr[0];
  #pragma unroll
  for (int j = 1; j < 4; ++j) wmax = max(wmax, lenr[j]);
  #pragma unroll
  for (int off = 1; off < 64; off <<= 1) wmax = max(wmax, __shfl_xor(wmax, off));

  const int arow = wave * 16 + n16;
  const u32 swz  = (u32)((n16 & 7) << 4);

  u16* hb = local ? hbufL + (size_t)xcd * 2 * BBHH : hbufG;
  u32* fb = local ? flagsL + (xcd * 4 + wave) * 32 : flagsG + wave * 32;
  u32* myf = fb + slot;
  const u32* pollp = fb + (lane & 31);

  __syncthreads();   // weights staged

  // prologue: xe fragments for t=0
  bh8 xf[8];
  {
    const u16* px = xe + (size_t)arow * EE + grp * 8;
    #pragma unroll
    for (int k = 0; k < 8; ++k) xf[k] = *(const bh8*)(px + k * 32);
  }

  for (int t = 0; t < TT; ++t) {
    if (t > wmax) break;

    // input GEMM: pure-register MFMA (off the sync critical path)
    f32x4 acc[4];
    #pragma unroll
    for (int q = 0; q < 4; ++q) acc[q] = (f32x4){bsq[q], bsq[q], bsq[q], bsq[q]};
    #pragma unroll
    for (int kk = 0; kk < 8; ++kk) {
      #pragma unroll
      for (int q = 0; q < 4; ++q)
        acc[q] = __builtin_amdgcn_mfma_f32_16x16x32_bf16(xf[kk], wihf[q * 8 + kk], acc[q], 0, 0, 0);
    }

    // wait for step-t h from the 32 producers of this (xcd, wave) group
    if (t > 0) {
      u32 v;
      do { v = ldf(pollp, local); } while (v < (u32)t);
    }

    // h fragments (L2-coherent in local mode)
    const u16* ph = hb + (size_t)(t & 1) * BBHH + (size_t)arow * HH + grp * 8;
    bh8 hf[16];
    #pragma unroll
    for (int k = 0; k < 16; ++k) hf[k] = ldh(ph + k * 32, local);
    asm volatile("s_waitcnt vmcnt(0)" ::: "memory");
    __builtin_amdgcn_sched_barrier(0);

    // xe prefetch for t+1 (overlaps recurrent GEMM)
    {
      const int tn = (t + 1 < TT) ? t + 1 : t;
      const u16* px = xe + ((size_t)tn * BB + arow) * EE + grp * 8;
      #pragma unroll
      for (int k = 0; k < 8; ++k) xf[k] = *(const bh8*)(px + k * 32);
    }

    // recurrent GEMM from LDS
    #pragma unroll
    for (int kk = 0; kk < 16; ++kk) {
      const u32 o = ((u32)(kk * 64 + grp * 16)) ^ swz;
      #pragma unroll
      for (int q = 0; q < 4; ++q) {
        bh8 b = *(const bh8*)((const char*)lWhh + (u32)((q * 16 + n16) * 1024) + o);
        acc[q] = __builtin_amdgcn_mfma_f32_16x16x32_bf16(hf[kk], b, acc[q], 0, 0, 0);
      }
    }

    // epilogue: C row = grp*4+j (batch), col = n16 (unit); i/f/g/o in-lane
    u16* hw = hb + (size_t)((t & 1) ^ 1) * BBHH;
    #pragma unroll
    for (int j = 0; j < 4; ++j) {
      const int brow = wave * 16 + grp * 4 + j;
      const float iv = sigm(acc[0][j]);
      const float ff = sigm(acc[1][j]);
      const float gv = tanh_f(acc[2][j]);
      const float oo = sigm(acc[3][j]);
      const float cn = ff * cst[j] + iv * gv;
      const float hn = oo * tanh_f(cn);
      const bool valid = (t < lenr[j]);        // packed-seq freeze
      cst[j] = valid ? cn : cst[j];
      hst[j] = valid ? hn : hst[j];
      u32 hv = (u32)f2b(hst[j]);
      u32 up = __shfl_xor(hv, 1);
      // store through t==len so BOTH parity buffers hold the frozen value
      if (((n16 & 1) == 0) && (t <= lenr[j]))
        st32((u32*)(hw + (size_t)brow * HH + slot * 16 + n16), hv | (up << 16), local);
    }

    // release: h stores retired at coherence point -> publish flag
    asm volatile("s_waitcnt vmcnt(0)" ::: "memory");
    if (lane == 0) st32(myf, (u32)(t + 1), local);
  }

  // drained: park flag, then write final h to hout (plain cached stores)
  asm volatile("s_waitcnt vmcnt(0)" ::: "memory");
  if (lane == 0) st32(myf, (u32)(TT + 1), local);
  #pragma unroll
  for (int j = 0; j < 4; ++j) {
    const int brow = wave * 16 + grp * 4 + j;
    u32 hv = (u32)f2b(hst[j]);
    u32 up = __shfl_xor(hv, 1);
    if ((n16 & 1) == 0)
      *(u32*)(hout + (size_t)brow * HH + slot * 16 + n16) = hv | (up << 16);
  }
}

// ---- kernel 3: out[b] = sigmoid(h_last[b] . fc_w + fc_b) ----
__global__ __launch_bounds__(64) void k_fc(const u16* __restrict__ hout,
    const float* __restrict__ fcw, const float* __restrict__ fcb,
    float* __restrict__ out)
{
  const int b = blockIdx.x;
  const int lane = threadIdx.x;
  const u16* hr = hout + (size_t)b * HH;
  float s = 0.f;
  #pragma unroll
  for (int j = 0; j < 8; ++j) {
    const int u = lane + j * 64;
    s += b2f(hr[u]) * fcw[u];
  }
  #pragma unroll
  for (int off = 32; off > 0; off >>= 1) s += __shfl_xor(s, off);
  if (lane == 0) out[b] = sigm(s + fcb[0]);
}

extern "C" void kernel_launch(void* const* d_in, const int* in_sizes, int n_in,
                              void* d_out, int out_size, void* d_ws, size_t ws_size,
                              hipStream_t stream)
{
  const int*   x    = (const int*)  d_in[0];
  const int*   xlen = (const int*)  d_in[1];
  const float* emb  = (const float*)d_in[2];
  const float* Wih  = (const float*)d_in[3];
  const float* Whh  = (const float*)d_in[4];
  const float* bih  = (const float*)d_in[5];
  const float* bhh  = (const float*)d_in[6];
  const float* fcw  = (const float*)d_in[7];
  const float* fcb  = (const float*)d_in[8];
  float* out = (float*)d_out;

  char* ws = (char*)d_ws;
  u32* regp   = (u32*)(ws + WS_REG);
  u32* flagsL = (u32*)(ws + WS_FLAGSL);
  u32* flagsG = (u32*)(ws + WS_FLAGSG);
  u16* hbufL  = (u16*)(ws + WS_HBUFL);
  u16* hbufG  = (u16*)(ws + WS_HBUFG);
  u16* hout   = (u16*)(ws + WS_HOUT);
  u16* xe     = (u16*)(ws + WS_XE);

  (void)hipFuncSetAttribute((const void*)k_lstm,
      hipFuncAttributeMaxDynamicSharedMemorySize, 98304);

  k_init <<<dim3(1216), dim3(256), 0, stream>>>((u32*)ws);
  k_embed<<<dim3((TT * BB * EE / 8) / 256), dim3(256), 0, stream>>>(x, emb, xe);
  k_lstm <<<dim3(NWG), dim3(THREADS), 98304, stream>>>(Whh, Wih, bih, bhh, xe, xlen,
                                                       regp, flagsL, flagsG, hbufL, hbufG, hout);
  k_fc   <<<dim3(BB), dim3(64), 0, stream>>>(hout, fcw, fcb, out);
}

// Round 8
// 2855.193 us; speedup vs baseline: 1.3789x; 1.3789x over previous
//
#include <hip/hip_runtime.h>

#define TT 512
#define BB 64
#define EE 256
#define HH 512
#define NWG 64
#define THREADS 256
#define BBHH (BB * HH)

typedef unsigned short u16;
typedef unsigned int u32;
typedef unsigned long long u64;
typedef __attribute__((ext_vector_type(8))) short bh8;
typedef __attribute__((ext_vector_type(4))) float f32x4;

__device__ __forceinline__ u16 f2b(float f) {
  union { float f; u32 u; } v; v.f = f;
  return (u16)((v.u + 0x7fffu + ((v.u >> 16) & 1u)) >> 16);
}
__device__ __forceinline__ float b2f(u16 b) {
  union { u32 u; float f; } v; v.u = ((u32)b) << 16; return v.f;
}
__device__ __forceinline__ float sigm(float x) { return 1.f / (1.f + __expf(-x)); }
__device__ __forceinline__ float tanh_f(float x) {
  float e = __expf(2.f * x);
  return 1.f - 2.f / (e + 1.f);
}

// uncached (IF-coherent) primitives — round-2-proven sc0 sc1 encoding
__device__ __forceinline__ bh8 ldh16(const u16* p) {   // 16B h-fragment load
  bh8 v;
  asm volatile("global_load_dwordx4 %0, %1, off sc0 sc1" : "=v"(v) : "v"(p));
  return v;
}
__device__ __forceinline__ u32 ldf16(const u16* p) {   // u16 flag load
  u32 v;
  asm volatile("global_load_ushort %0, %1, off sc0 sc1\n\ts_waitcnt vmcnt(0)"
               : "=v"(v) : "v"(p) : "memory");
  return v;
}
__device__ __forceinline__ void stf16(u16* p, u32 v) { // u16 flag store
  asm volatile("global_store_short %0, %1, off sc0 sc1" :: "v"(p), "v"(v) : "memory");
}

// ws layout: [flags 4KB][xe 16MB][hbuf 2*64KB parity]
// flags: u16 flags[4][64] — group v's 64 flags packed in 128B (2 lines/poll).

// ---- kernel 0: zero flags + h parity buffers (ws is poisoned 0xAA) ----
__global__ void k_init(u32* __restrict__ flags, u32* __restrict__ hb) {
  const int gid = blockIdx.x * 256 + threadIdx.x;   // 128 blocks -> 32768
  if (gid < 1024) flags[gid] = 0u;                  // 4 KB
  if (gid < 32768) hb[gid] = 0u;                    // 128 KB
}

// ---- kernel 1: xe[t][b][e] = bf16(emb[x[t,b]][e]) ----
__global__ __launch_bounds__(256) void k_embed(const int* __restrict__ x,
    const float* __restrict__ emb, u16* __restrict__ xe)
{
  const int gid = blockIdx.x * 256 + threadIdx.x;  // TT*BB*EE/8 threads
  const int tb  = gid >> 5;
  const int e0  = (gid & 31) << 3;
  const int tok = x[tb];
  const float4* s = (const float4*)(emb + (size_t)tok * EE + e0);
  float4 a = s[0], b = s[1];
  u16 o[8] = { f2b(a.x), f2b(a.y), f2b(a.z), f2b(a.w),
               f2b(b.x), f2b(b.y), f2b(b.z), f2b(b.w) };
  *(uint4*)(xe + (size_t)tb * EE + e0) = *(uint4*)o;
}

// ---- kernel 2: persistent gate-partitioned LSTM, fence-free sync ----
// WG w owns hidden units [8w,8w+8) -> 32 gate rows = 2 MFMA N-tiles.
// Wave v owns batch rows [16v,16v+16): 4 independent sync groups of 64 waves.
// h exchanged through IF via uncached (sc0 sc1) stores/loads; flags are u16
// packed 128B/group so a poll touches 2 cache lines (was 64 in round 2).
__global__ __launch_bounds__(THREADS, 1) void k_lstm(
    const float* __restrict__ Whh, const float* __restrict__ Wih,
    const float* __restrict__ bih, const float* __restrict__ bhh,
    const u16* __restrict__ xe, const int* __restrict__ xlen,
    u16* __restrict__ hbuf, u16* __restrict__ flags)
{
  __shared__ u16 lWhh[32 * HH];   // 32 KB, bf16, XOR-swizzled rows
  __shared__ u16 lWih[32 * EE];   // 16 KB

  const int wg   = blockIdx.x;
  const int tid  = threadIdx.x;
  const int wave = tid >> 6;
  const int lane = tid & 63;
  const int n16  = lane & 15;
  const int grp  = lane >> 4;

  // ---- stage weight slices (f32 -> bf16) into LDS, swizzle byte ^= (row&7)<<4
  #pragma unroll
  for (int it = 0; it < 8; ++it) {
    int idx = it * THREADS + tid;
    int n   = idx >> 6;
    int c0  = (idx & 63) << 3;
    int grow = (n >> 3) * HH + wg * 8 + (n & 7);
    const float* s = Whh + (size_t)grow * HH + c0;
    u16 tmp[8];
    #pragma unroll
    for (int j = 0; j < 8; ++j) tmp[j] = f2b(s[j]);
    *(uint4*)((char*)lWhh + (u32)(n * 1024 + ((c0 << 1) ^ ((n & 7) << 4)))) = *(uint4*)tmp;
  }
  #pragma unroll
  for (int it = 0; it < 4; ++it) {
    int idx = it * THREADS + tid;
    int n   = idx >> 5;
    int c0  = (idx & 31) << 3;
    int grow = (n >> 3) * HH + wg * 8 + (n & 7);
    const float* s = Wih + (size_t)grow * EE + c0;
    u16 tmp[8];
    #pragma unroll
    for (int j = 0; j < 8; ++j) tmp[j] = f2b(s[j]);
    *(uint4*)((char*)lWih + (u32)(n * 512 + ((c0 << 1) ^ ((n & 7) << 4)))) = *(uint4*)tmp;
  }

  // bias sums for this lane's two gate rows (tile0: i/f, tile1: g/o)
  const int r0 = (n16 < 8) ? (wg * 8 + n16) : (HH + wg * 8 + (n16 - 8));
  const int r1 = (n16 < 8) ? (2 * HH + wg * 8 + n16) : (3 * HH + wg * 8 + (n16 - 8));
  const float bs0 = bih[r0] + bhh[r0];
  const float bs1 = bih[r1] + bhh[r1];

  int   lenr[4];
  int   mrow[4];
  float cst[4] = {0.f, 0.f, 0.f, 0.f};
  float hst[4] = {0.f, 0.f, 0.f, 0.f};
  #pragma unroll
  for (int r = 0; r < 4; ++r) { mrow[r] = wave * 16 + grp * 4 + r; lenr[r] = xlen[mrow[r]]; }
  int wmax = lenr[0];
  #pragma unroll
  for (int r = 1; r < 4; ++r) wmax = max(wmax, lenr[r]);
  #pragma unroll
  for (int off = 1; off < 64; off <<= 1) wmax = max(wmax, __shfl_xor(wmax, off));

  const int  arow = wave * 16 + n16;            // A-fragment batch row
  const u32  swz  = (u32)((n16 & 7) << 4);
  const char* pWhh0 = (const char*)lWhh + n16 * 1024;
  const char* pWhh1 = (const char*)lWhh + (16 + n16) * 1024;
  const char* pWih0 = (const char*)lWih + n16 * 512;
  const char* pWih1 = (const char*)lWih + (16 + n16) * 512;

  u16* myf = flags + wave * 64 + wg;            // this wave's flag
  const u16* pf = flags + wave * 64 + lane;     // flag this lane polls

  __syncthreads();   // weights staged (only barrier in the kernel)

  // prologue: xe fragments for t=0
  bh8 xf[8];
  {
    const u16* px = xe + (size_t)arow * EE + grp * 8;
    #pragma unroll
    for (int k = 0; k < 8; ++k) xf[k] = *(const bh8*)(px + k * 32);
  }

  for (int t = 0; t < TT; ++t) {
    if (t > wmax) break;                        // group drained: exit

    // ---- input GEMM first: needs only xf + LDS (off the sync critical path)
    f32x4 acc0 = {bs0, bs0, bs0, bs0};
    f32x4 acc1 = {bs1, bs1, bs1, bs1};
    #pragma unroll
    for (int k = 0; k < 8; ++k) {
      const u32 o = ((u32)(k * 64 + grp * 16)) ^ swz;
      bh8 b0 = *(const bh8*)(pWih0 + o);
      bh8 b1 = *(const bh8*)(pWih1 + o);
      acc0 = __builtin_amdgcn_mfma_f32_16x16x32_bf16(xf[k], b0, acc0, 0, 0, 0);
      acc1 = __builtin_amdgcn_mfma_f32_16x16x32_bf16(xf[k], b1, acc1, 0, 0, 0);
    }

    // ---- wait for step-t h from all 64 WGs of this group (2-line poll)
    if (t > 0) {
      u32 v;
      do { v = ldf16(pf); } while (v < (u32)t);
      asm volatile("" ::: "memory");
    }

    // ---- h A-fragments: uncached dwordx4 (16 requests/wave)
    const u16* ph = hbuf + (size_t)(t & 1) * BBHH + (size_t)arow * HH + grp * 8;
    bh8 hf[16];
    #pragma unroll
    for (int k = 0; k < 16; ++k) hf[k] = ldh16(ph + k * 32);

    // ---- xe prefetch for t+1 (overlaps h-load latency; xf already consumed)
    {
      const int tn = (t + 1 < TT) ? t + 1 : t;
      const u16* px = xe + ((size_t)tn * BB + arow) * EE + grp * 8;
      #pragma unroll
      for (int k = 0; k < 8; ++k) xf[k] = *(const bh8*)(px + k * 32);
    }
    asm volatile("s_waitcnt vmcnt(0)" ::: "memory");
    __builtin_amdgcn_sched_barrier(0);

    // ---- recurrent GEMM
    #pragma unroll
    for (int k = 0; k < 16; ++k) {
      const u32 o = ((u32)(k * 64 + grp * 16)) ^ swz;
      bh8 b0 = *(const bh8*)(pWhh0 + o);
      bh8 b1 = *(const bh8*)(pWhh1 + o);
      acc0 = __builtin_amdgcn_mfma_f32_16x16x32_bf16(hf[k], b0, acc0, 0, 0, 0);
      acc1 = __builtin_amdgcn_mfma_f32_16x16x32_bf16(hf[k], b1, acc1, 0, 0, 0);
    }

    // ---- epilogue: C row = grp*4+r (batch), col = n16 (gate unit)
    u16* hw = hbuf + (size_t)((t & 1) ^ 1) * BBHH;
    #pragma unroll
    for (int r = 0; r < 4; ++r) {
      const float v0 = acc0[r];                 // i (n16<8) / f (n16>=8)
      const float v1 = acc1[r];                 // g / o
      const float fv = __shfl_xor(v0, 8);
      const float ov = __shfl_xor(v1, 8);
      const float iv = sigm(v0);
      const float ff = sigm(fv);
      const float gv = tanh_f(v1);
      const float oo = sigm(ov);
      const float cn = ff * cst[r] + iv * gv;
      const float hn = oo * tanh_f(cn);
      const bool valid = (t < lenr[r]);         // packed-seq freeze
      cst[r] = valid ? cn : cst[r];
      hst[r] = valid ? hn : hst[r];
      u32 hv = (u32)f2b(hst[r]);
      u32 up = __shfl_xor(hv, 1);
      // store through t==len so BOTH parity buffers hold the frozen value
      if (((n16 & 1) == 0) && (n16 < 8) && (t <= lenr[r]))
        __hip_atomic_store((u32*)(hw + (size_t)mrow[r] * HH + wg * 8 + n16),
                           hv | (up << 16), __ATOMIC_RELAXED, __HIP_MEMORY_SCOPE_AGENT);
    }

    // ---- release: uncached stores ack'd at IF -> publish flag
    asm volatile("s_waitcnt vmcnt(0)" ::: "memory");
    if (lane == 0) stf16(myf, (u32)(t + 1));
  }

  // drained: park flag past the horizon so nobody ever waits on this wave
  asm volatile("s_waitcnt vmcnt(0)" ::: "memory");
  if (lane == 0) stf16(myf, (u32)(TT + 1));
}

// ---- kernel 3: out[b] = sigmoid(h_last[b] . fc_w + fc_b) ----
__global__ __launch_bounds__(64) void k_fc(const u16* __restrict__ h0,
    const float* __restrict__ fcw, const float* __restrict__ fcb,
    float* __restrict__ out)
{
  const int b = blockIdx.x;
  const int lane = threadIdx.x;
  const u16* hr = h0 + (size_t)b * HH;
  float s = 0.f;
  #pragma unroll
  for (int j = 0; j < 8; ++j) {
    const int u = lane + j * 64;
    s += b2f(hr[u]) * fcw[u];
  }
  #pragma unroll
  for (int off = 32; off > 0; off >>= 1) s += __shfl_xor(s, off);
  if (lane == 0) out[b] = sigm(s + fcb[0]);
}

extern "C" void kernel_launch(void* const* d_in, const int* in_sizes, int n_in,
                              void* d_out, int out_size, void* d_ws, size_t ws_size,
                              hipStream_t stream)
{
  const int*   x    = (const int*)  d_in[0];
  const int*   xlen = (const int*)  d_in[1];
  const float* emb  = (const float*)d_in[2];
  const float* Wih  = (const float*)d_in[3];
  const float* Whh  = (const float*)d_in[4];
  const float* bih  = (const float*)d_in[5];
  const float* bhh  = (const float*)d_in[6];
  const float* fcw  = (const float*)d_in[7];
  const float* fcb  = (const float*)d_in[8];
  float* out = (float*)d_out;

  char* ws = (char*)d_ws;
  u16* flags = (u16*)ws;                                   // 4 KB slot
  u16* xe    = (u16*)(ws + 4096);                          // 16 MB
  u16* hbuf  = (u16*)(ws + 4096 + (size_t)TT * BB * EE * 2); // 128 KB parity

  k_init <<<dim3(128), dim3(256), 0, stream>>>((u32*)flags, (u32*)hbuf);
  k_embed<<<dim3((TT * BB * EE / 8) / 256), dim3(256), 0, stream>>>(x, emb, xe);
  k_lstm <<<dim3(NWG), dim3(THREADS), 0, stream>>>(Whh, Wih, bih, bhh, xe, xlen, hbuf, flags);
  k_fc   <<<dim3(BB), dim3(64), 0, stream>>>(hbuf, fcw, fcb, out);
}